// Round 2
// baseline (427.081 us; speedup 1.0000x reference)
//
#include <hip/hip_runtime.h>
#include <stdint.h>

typedef unsigned short u16;
typedef unsigned int   u32;

#define NTOK   32768      // B*P
#define GD     768
#define GH     256
#define GH2    128
#define GE     64

typedef __bf16 bf16x8 __attribute__((ext_vector_type(8)));
typedef float  f32x4  __attribute__((ext_vector_type(4)));
union Frag { uint4 u; bf16x8 b; };

__device__ __forceinline__ float bf2f(u16 h) {
  union { u32 u; float f; } v; v.u = ((u32)h) << 16; return v.f;
}
__device__ __forceinline__ u16 f2bf(float f) {
  union { float f; u32 u; } v; v.f = f;
  u32 r = (v.u + 0x7fffu + ((v.u >> 16) & 1u)) >> 16;
  return (u16)r;
}

__device__ __forceinline__ void async16(void* lds, const void* g) {
  __builtin_amdgcn_global_load_lds(
      (const __attribute__((address_space(1))) void*)g,
      (__attribute__((address_space(3))) void*)lds, 16, 0, 0);
}

// prop is int64 in the reference but the harness may hand us int32.
// Layout-detect at runtime: for int64 (values 0..63) every odd 32-bit word is 0.
__device__ __forceinline__ int getProp(const int* p32, int t, int is64) {
  return is64 ? p32[2 * t] : p32[t];
}

// ---------------- workspace layout (bytes) ----------------
static const size_t OFF_Y    = 0;            // bf16 NTOK*768*2 = 50331648
static const size_t OFF_W1T  = 50331648;     // bf16 64*256*768*2 = 25165824
static const size_t OFF_W2T  = 75497472;     // bf16 64*128*256*2 = 4194304
static const size_t OFF_TOK  = 79691776;     // int  NTOK*4
static const size_t OFF_META = 79822848;     // 8 KB ints
// meta: counts[64]@0, cursors[64]@64, offsets[65]@128, tileHead[512]@256,
//       tileRow[512]@768, nTiles@1280, propIs64@1284

// ---------------- K0: zero outputs + metadata ----------------
__global__ void prep_kernel(u32* __restrict__ outz, int* __restrict__ meta) {
  int t = blockIdx.x * 256 + threadIdx.x;   // grid 256 -> 65536 threads
  outz[t] = 0u;                             // 65536 fp32 output elements
  if (t < 2048) meta[t] = 0;
}

// ---------------- K0b: detect int32 vs int64 properties ----------------
__global__ void prop_probe(const int* __restrict__ p32, int* __restrict__ flag) {
  const int ln = threadIdx.x;   // 1 wave
  int v = 0;
#pragma unroll
  for (int j = 0; j < 8; ++j) v |= p32[2 * (ln * 8 + j) + 1];
#pragma unroll
  for (int d = 1; d < 64; d <<= 1) v |= __shfl_xor(v, d);
  if (ln == 0) *flag = (v == 0) ? 1 : 0;
}

// ---------------- K1: fp32 [E][R][C] -> bf16 [E][C][R] transpose ----------------
__global__ void transpose_kernel(const float* __restrict__ in, u16* __restrict__ out,
                                 int R, int C, int tilesC) {
  __shared__ u16 tile[32][33];
  const int tilesPerMat = (R >> 5) * tilesC;
  const int e  = blockIdx.x / tilesPerMat;
  const int t  = blockIdx.x % tilesPerMat;
  const int tr = t / tilesC, tc = t % tilesC;
  const size_t mat = (size_t)e * R * C;
  const int tx = threadIdx.x & 31, ty = threadIdx.x >> 5;
  const int r0 = tr * 32, c0 = tc * 32;
#pragma unroll
  for (int i = 0; i < 32; i += 8)
    tile[ty + i][tx] = f2bf(in[mat + (size_t)(r0 + ty + i) * C + c0 + tx]);
  __syncthreads();
#pragma unroll
  for (int i = 0; i < 32; i += 8)
    out[mat + (size_t)(c0 + ty + i) * R + r0 + tx] = tile[tx][ty + i];
}

// ---------------- K2: LayerNorm -> y bf16 + head histogram ----------------
__global__ void ln_kernel(const float* __restrict__ hs, const float* __restrict__ g,
                          const float* __restrict__ bta, const int* __restrict__ prop,
                          const float* __restrict__ mask, u16* __restrict__ y,
                          int* __restrict__ counts, const int* __restrict__ flag) {
  const int wv = threadIdx.x >> 6, ln = threadIdx.x & 63;
  const int t = blockIdx.x * 4 + wv;          // grid 8192
  const float* x = hs + (size_t)t * GD;
  float v[12];
  float s = 0.f, sq = 0.f;
#pragma unroll
  for (int c = 0; c < 3; ++c) {
    float4 u = *(const float4*)(x + c * 256 + ln * 4);
    v[c*4+0] = u.x; v[c*4+1] = u.y; v[c*4+2] = u.z; v[c*4+3] = u.w;
    s  += u.x + u.y + u.z + u.w;
    sq += u.x*u.x + u.y*u.y + u.z*u.z + u.w*u.w;
  }
#pragma unroll
  for (int d = 1; d < 64; d <<= 1) { s += __shfl_xor(s, d); sq += __shfl_xor(sq, d); }
  const float mu = s * (1.f / 768.f);
  const float rstd = rsqrtf(sq * (1.f / 768.f) - mu * mu + 1e-5f);
  const int is64 = *flag;
  const int p = getProp(prop, t, is64);
  const float* gp = g + (size_t)p * GD;
  const float* bp = bta + (size_t)p * GD;
  u16* yp = y + (size_t)t * GD;
#pragma unroll
  for (int c = 0; c < 3; ++c) {
    float4 ug = *(const float4*)(gp + c * 256 + ln * 4);
    float4 ub = *(const float4*)(bp + c * 256 + ln * 4);
    float y0 = (v[c*4+0] - mu) * rstd * ug.x + ub.x;
    float y1 = (v[c*4+1] - mu) * rstd * ug.y + ub.y;
    float y2 = (v[c*4+2] - mu) * rstd * ug.z + ub.z;
    float y3 = (v[c*4+3] - mu) * rstd * ug.w + ub.w;
    uint2 o;
    o.x = (u32)f2bf(y0) | ((u32)f2bf(y1) << 16);
    o.y = (u32)f2bf(y2) | ((u32)f2bf(y3) << 16);
    *(uint2*)(yp + c * 256 + ln * 4) = o;
  }
  if (ln == 0 && mask[t] > 0.f) atomicAdd(&counts[p], 1);
}

// ---------------- K3: scan + tile table (1 wave) ----------------
__global__ void scan_kernel(const int* __restrict__ counts, int* __restrict__ offsets,
                            int* __restrict__ tileHead, int* __restrict__ tileRow,
                            int* __restrict__ nTilesPtr, int* __restrict__ cursors) {
  const int e = threadIdx.x;  // 0..63
  int c = counts[e];
  int inc = c;
#pragma unroll
  for (int d = 1; d < 64; d <<= 1) { int n = __shfl_up(inc, d); if (e >= d) inc += n; }
  const int off = inc - c;
  offsets[e] = off;
  if (e == 63) offsets[64] = inc;
  int ntile = (c + 127) >> 7;
  int inct = ntile;
#pragma unroll
  for (int d = 1; d < 64; d <<= 1) { int n = __shfl_up(inct, d); if (e >= d) inct += n; }
  const int tb = inct - ntile;
  for (int j = 0; j < ntile; ++j) { tileHead[tb + j] = e; tileRow[tb + j] = off + j * 128; }
  if (e == 63) *nTilesPtr = inct;
  cursors[e] = 0;
}

// ---------------- K4: bucket token ids by head ----------------
__global__ void scatter_kernel(const int* __restrict__ prop, const float* __restrict__ mask,
                               const int* __restrict__ offsets, int* __restrict__ cursors,
                               int* __restrict__ tokenIds, const int* __restrict__ flag) {
  const int t = blockIdx.x * 256 + threadIdx.x;  // grid 128
  if (mask[t] > 0.f) {
    const int p = getProp(prop, t, *flag);
    const int pos = atomicAdd(&cursors[p], 1);
    tokenIds[offsets[p] + pos] = t;
  }
}

// ---------------- K5: grouped fused adapter GEMM (54.3 KB LDS) ----------------
__global__ __launch_bounds__(256, 1) void adapter_gemm(
    const u16* __restrict__ y, const u16* __restrict__ w1t, const u16* __restrict__ w2t,
    const float* __restrict__ b1, const float* __restrict__ b2,
    const float* __restrict__ w3, const float* __restrict__ b3,
    const float* __restrict__ base, const float* __restrict__ mask,
    const int* __restrict__ tokenIds, const int* __restrict__ offsets,
    const int* __restrict__ tileHead, const int* __restrict__ tileRow,
    const int* __restrict__ nTilesPtr, float* __restrict__ outp) {
  __shared__ u16 sA[128 * 32];     //  8 KB   y k-tile [row][32]
  __shared__ u16 sH[128 * 136];    // 34 KB   h1-half / h2 (aliased), stride 136
  __shared__ u16 sB[128 * 32];     //  8 KB   B k-tile [n][32]
  __shared__ float sBias1[256];
  __shared__ float sBias2[128];
  __shared__ float sW3[2][128];
  __shared__ float sB3[2];
  __shared__ int   sTok[128];

  const int tid  = threadIdx.x;
  const int wv   = tid >> 6;
  const int l15  = tid & 15;
  const int quad = (tid & 63) >> 4;
  const int arow = tid >> 2;            // 0..63
  const int koff = (tid & 3) * 8;       // elements: 0,8,16,24
  const f32x4 vzero = {0.f, 0.f, 0.f, 0.f};
  const int nt = *nTilesPtr;

  for (int tile = blockIdx.x; tile < nt; tile += gridDim.x) {
    __syncthreads();  // protect LDS/meta reuse across tiles
    const int e  = tileHead[tile];
    const int rs = tileRow[tile];
    const int nRows = min(128, offsets[e + 1] - rs);

    if (tid < 128) sTok[tid] = tokenIds[rs + min(tid, nRows - 1)];
    sBias1[tid] = b1[e * GH + tid];
    if (tid < 128) sBias2[tid] = b2[e * GH2 + tid];
    { const int k = tid >> 1, o = tid & 1; sW3[o][k] = w3[e * GH2 * 2 + k * 2 + o]; }
    if (tid < 2) sB3[tid] = b3[e * 2 + tid];
    __syncthreads();

    const u16* yrow0 = y + (size_t)sTok[arow] * GD;
    const u16* yrow1 = y + (size_t)sTok[64 + arow] * GD;
    const u16* w1e = w1t + (size_t)e * GH * GD;
    const u16* w2e = w2t + (size_t)e * GH2 * GH;

    f32x4 acc2[8][2];     // GEMM2 result: 128 rows x 128 cols (wave: 32 cols)
#pragma unroll
    for (int f = 0; f < 8; ++f)
#pragma unroll
      for (int g = 0; g < 2; ++g) acc2[f][g] = vzero;

    // -------- two phases over the H=256 hidden dim (128 cols each) --------
    for (int c = 0; c < 2; ++c) {
      // ---- GEMM1 half: y[128x768] @ W1[768, c*128..c*128+127] ----
      f32x4 acc1[8][2];
#pragma unroll
      for (int f = 0; f < 8; ++f)
#pragma unroll
        for (int g = 0; g < 2; ++g) acc1[f][g] = vzero;

      for (int kt = 0; kt < 24; ++kt) {
        const int k0 = kt * 32;
        async16(sA + wv * 512,        yrow0 + k0 + koff);
        async16(sA + 2048 + wv * 512, yrow1 + k0 + koff);
#pragma unroll
        for (int j = 0; j < 2; ++j)
          async16(sB + j * 2048 + wv * 512,
                  w1e + (size_t)(c * 128 + j * 64 + arow) * GD + k0 + koff);
        __syncthreads();

        Frag fa[8], fb[2];
#pragma unroll
        for (int f = 0; f < 8; ++f)
          fa[f].u = *(const uint4*)&sA[(f * 16 + l15) * 32 + quad * 8];
#pragma unroll
        for (int g = 0; g < 2; ++g)
          fb[g].u = *(const uint4*)&sB[(wv * 32 + g * 16 + l15) * 32 + quad * 8];
#pragma unroll
        for (int f = 0; f < 8; ++f)
#pragma unroll
          for (int g = 0; g < 2; ++g)
            acc1[f][g] = __builtin_amdgcn_mfma_f32_16x16x32_bf16(fa[f].b, fb[g].b, acc1[f][g], 0, 0, 0);
        __syncthreads();
      }

      // epilogue 1: +b1, relu -> sH (local cols 0..127 of this half)
#pragma unroll
      for (int f = 0; f < 8; ++f)
#pragma unroll
        for (int g = 0; g < 2; ++g) {
          const int col = wv * 32 + g * 16 + l15;
          const float bias = sBias1[c * 128 + col];
#pragma unroll
          for (int r = 0; r < 4; ++r) {
            const int row = f * 16 + quad * 4 + r;
            sH[row * 136 + col] = f2bf(fmaxf(acc1[f][g][r] + bias, 0.f));
          }
        }
      __syncthreads();

      // ---- GEMM2 partial: h1half[128x128] @ W2[c*128..+127, 0..127] ----
      for (int kt = 0; kt < 4; ++kt) {
        const int k0 = kt * 32;
#pragma unroll
        for (int j = 0; j < 2; ++j)
          async16(sB + j * 2048 + wv * 512,
                  w2e + (size_t)(j * 64 + arow) * GH + c * 128 + k0 + koff);
        __syncthreads();

        Frag fa2[8], fb2[2];
#pragma unroll
        for (int f = 0; f < 8; ++f)
          fa2[f].u = *(const uint4*)&sH[(f * 16 + l15) * 136 + k0 + quad * 8];
#pragma unroll
        for (int g = 0; g < 2; ++g)
          fb2[g].u = *(const uint4*)&sB[(wv * 32 + g * 16 + l15) * 32 + quad * 8];
#pragma unroll
        for (int f = 0; f < 8; ++f)
#pragma unroll
          for (int g = 0; g < 2; ++g)
            acc2[f][g] = __builtin_amdgcn_mfma_f32_16x16x32_bf16(fa2[f].b, fb2[g].b, acc2[f][g], 0, 0, 0);
        __syncthreads();
      }
    }

    // epilogue 2: +b2, relu -> sH (now h2, 128x128)
#pragma unroll
    for (int f = 0; f < 8; ++f)
#pragma unroll
      for (int g = 0; g < 2; ++g) {
        const int col = wv * 32 + g * 16 + l15;
        const float bias = sBias2[col];
#pragma unroll
        for (int r = 0; r < 4; ++r) {
          const int row = f * 16 + quad * 4 + r;
          sH[row * 136 + col] = f2bf(fmaxf(acc2[f][g][r] + bias, 0.f));
        }
      }
    __syncthreads();

    // ---------- GEMM3 + residual + mask + scatter-store (fp32) ----------
    const int m = tid >> 1, o = tid & 1;
    if (m < nRows) {
      float a = sB3[o];
      const u16* h2row = &sH[m * 136];
#pragma unroll 16
      for (int k = 0; k < 128; ++k) a += bf2f(h2row[k]) * sW3[o][k];
      const int t = sTok[m];
      const float mk = mask[t];
      const float bs = base[t * 2 + o];
      outp[t * 2 + o] = (0.7f * a + 0.3f * bs) * mk;
    }
  }
}

extern "C" void kernel_launch(void* const* d_in, const int* in_sizes, int n_in,
                              void* d_out, int out_size, void* d_ws, size_t ws_size,
                              hipStream_t stream) {
  const float* hs   = (const float*)d_in[0];
  const float* base = (const float*)d_in[1];
  const int*   prop = (const int*)d_in[2];
  const float* mask = (const float*)d_in[3];
  const float* lng  = (const float*)d_in[4];
  const float* lnb  = (const float*)d_in[5];
  const float* W1   = (const float*)d_in[6];
  const float* b1   = (const float*)d_in[7];
  const float* W2   = (const float*)d_in[8];
  const float* b2   = (const float*)d_in[9];
  const float* W3   = (const float*)d_in[10];
  const float* b3   = (const float*)d_in[11];

  char* ws = (char*)d_ws;
  u16* y    = (u16*)(ws + OFF_Y);
  u16* w1t  = (u16*)(ws + OFF_W1T);
  u16* w2t  = (u16*)(ws + OFF_W2T);
  int* tok  = (int*)(ws + OFF_TOK);
  int* meta = (int*)(ws + OFF_META);
  int* counts   = meta;
  int* cursors  = meta + 64;
  int* offsets  = meta + 128;   // 65 ints
  int* tileHead = meta + 256;   // 512 ints
  int* tileRow  = meta + 768;   // 512 ints
  int* nTiles   = meta + 1280;
  int* propFlag = meta + 1284;

  prep_kernel<<<256, 256, 0, stream>>>((u32*)d_out, meta);
  prop_probe<<<1, 64, 0, stream>>>(prop, propFlag);
  transpose_kernel<<<64 * 24 * 8, 256, 0, stream>>>(W1, w1t, GD, GH, 8);
  transpose_kernel<<<64 * 8 * 4, 256, 0, stream>>>(W2, w2t, GH, GH2, 4);
  ln_kernel<<<NTOK / 4, 256, 0, stream>>>(hs, lng, lnb, prop, mask, y, counts, propFlag);
  scan_kernel<<<1, 64, 0, stream>>>(counts, offsets, tileHead, tileRow, nTiles, cursors);
  scatter_kernel<<<NTOK / 256, 256, 0, stream>>>(prop, mask, offsets, cursors, tok, propFlag);
  adapter_gemm<<<256, 256, 0, stream>>>(y, w1t, w2t, b1, b2, W3, b3, base, mask,
                                        tok, offsets, tileHead, tileRow, nTiles,
                                        (float*)d_out);
}

// Round 3
// 287.932 us; speedup vs baseline: 1.4833x; 1.4833x over previous
//
#include <hip/hip_runtime.h>
#include <stdint.h>

typedef unsigned short u16;
typedef unsigned int   u32;

#define NTOK   32768      // B*P
#define GD     768
#define GH     256
#define GH2    128
#define GE     64

typedef __bf16 bf16x8 __attribute__((ext_vector_type(8)));
typedef float  f32x4  __attribute__((ext_vector_type(4)));
union Frag { uint4 u; bf16x8 b; };

__device__ __forceinline__ float bf2f(u16 h) {
  union { u32 u; float f; } v; v.u = ((u32)h) << 16; return v.f;
}
__device__ __forceinline__ u16 f2bf(float f) {
  union { float f; u32 u; } v; v.f = f;
  u32 r = (v.u + 0x7fffu + ((v.u >> 16) & 1u)) >> 16;
  return (u16)r;
}

__device__ __forceinline__ void async16(void* lds, const void* g) {
  __builtin_amdgcn_global_load_lds(
      (const __attribute__((address_space(1))) void*)g,
      (__attribute__((address_space(3))) void*)lds, 16, 0, 0);
}

// prop is int64 in the reference; harness may hand us int32. Runtime-detect.
__device__ __forceinline__ int getProp(const int* p32, int t, int is64) {
  return is64 ? p32[2 * t] : p32[t];
}

// ---------------- workspace layout (bytes) ----------------
static const size_t OFF_Y    = 0;            // bf16 NTOK*768*2 = 50331648
static const size_t OFF_W1T  = 50331648;     // bf16 64*256*768*2 = 25165824
static const size_t OFF_W2T  = 75497472;     // bf16 64*128*256*2 = 4194304
static const size_t OFF_TOK  = 79691776;     // int  NTOK*4
static const size_t OFF_META = 79822848;     // 16 KB ints
// meta ints: counts_p[1024]@0 (bin e at e*16 -> 64B apart), cursors_p[1024]@1024,
// offsets[65]@2048, tileHead[512]@2176, tileRow[512]@2688, nTiles@3200, flag@3201

// ---------------- K0: zero outputs + metadata ----------------
__global__ void prep_kernel(u32* __restrict__ outz, int* __restrict__ meta) {
  int t = blockIdx.x * 256 + threadIdx.x;   // grid 256 -> 65536 threads
  outz[t] = 0u;                             // 65536 fp32 output elements
  if (t < 4096) meta[t] = 0;
}

// ---------------- K0b: detect int32 vs int64 properties ----------------
__global__ void prop_probe(const int* __restrict__ p32, int* __restrict__ flag) {
  const int ln = threadIdx.x;   // 1 wave
  int v = 0;
#pragma unroll
  for (int j = 0; j < 8; ++j) v |= p32[2 * (ln * 8 + j) + 1];
#pragma unroll
  for (int d = 1; d < 64; d <<= 1) v |= __shfl_xor(v, d);
  if (ln == 0) *flag = (v == 0) ? 1 : 0;
}

// ---------------- K0c: masked head histogram (LDS-binned, padded atomics) ----
__global__ void hist_kernel(const int* __restrict__ prop, const float* __restrict__ mask,
                            int* __restrict__ counts_p, const int* __restrict__ flag) {
  __shared__ int h[GE];
  const int tid = threadIdx.x;
  const int t = blockIdx.x * 256 + tid;     // grid 128
  if (tid < GE) h[tid] = 0;
  __syncthreads();
  if (mask[t] > 0.f) atomicAdd(&h[getProp(prop, t, *flag)], 1);
  __syncthreads();
  if (tid < GE && h[tid] > 0) atomicAdd(&counts_p[tid * 16], h[tid]);
}

// ---------------- K1a: W1 fp32 [64][768][256] -> bf16 [64][256][768] ----------
__global__ void transpose_w1(const float* __restrict__ in, u16* __restrict__ out) {
  __shared__ u16 tl[64][260];               // [h][d], 33.3 KB
  const int bid = blockIdx.x;               // grid 64*3*4 = 768
  const int e  = bid / 12, r = bid % 12;
  const int d0 = (r / 4) * 256, h0 = (r % 4) * 64;
  const int tid = threadIdx.x;
  const size_t inMat = (size_t)e * GD * GH;
  const size_t outMat = (size_t)e * GH * GD;
  const int h_l = (tid & 15) * 4, d_l = tid >> 4;
#pragma unroll
  for (int dd = 0; dd < 16; ++dd) {
    const int d = d_l + dd * 16;
    float4 v = *(const float4*)(in + inMat + (size_t)(d0 + d) * GH + h0 + h_l);
    tl[h_l + 0][d] = f2bf(v.x);
    tl[h_l + 1][d] = f2bf(v.y);
    tl[h_l + 2][d] = f2bf(v.z);
    tl[h_l + 3][d] = f2bf(v.w);
  }
  __syncthreads();
  const int wv = tid >> 6, ln = tid & 63;
#pragma unroll
  for (int hh = 0; hh < 16; ++hh) {
    const int h = wv * 16 + hh;
    *(uint2*)(out + outMat + (size_t)(h0 + h) * GD + d0 + ln * 4) =
        *(const uint2*)&tl[h][ln * 4];
  }
}

// ---------------- K1b: generic fp32 [E][R][C] -> bf16 [E][C][R] (for W2) ------
__global__ void transpose_kernel(const float* __restrict__ in, u16* __restrict__ out,
                                 int R, int C, int tilesC) {
  __shared__ u16 tile[32][33];
  const int tilesPerMat = (R >> 5) * tilesC;
  const int e  = blockIdx.x / tilesPerMat;
  const int t  = blockIdx.x % tilesPerMat;
  const int tr = t / tilesC, tc = t % tilesC;
  const size_t mat = (size_t)e * R * C;
  const int tx = threadIdx.x & 31, ty = threadIdx.x >> 5;
  const int r0 = tr * 32, c0 = tc * 32;
#pragma unroll
  for (int i = 0; i < 32; i += 8)
    tile[ty + i][tx] = f2bf(in[mat + (size_t)(r0 + ty + i) * C + c0 + tx]);
  __syncthreads();
#pragma unroll
  for (int i = 0; i < 32; i += 8)
    out[mat + (size_t)(c0 + ty + i) * R + r0 + tx] = tile[tx][ty + i];
}

// ---------------- K2: LayerNorm -> y bf16 (pure stream, no atomics) -----------
__global__ void ln_kernel(const float* __restrict__ hs, const float* __restrict__ g,
                          const float* __restrict__ bta, const int* __restrict__ prop,
                          u16* __restrict__ y, const int* __restrict__ flag) {
  const int wv = threadIdx.x >> 6, ln = threadIdx.x & 63;
  const int t = blockIdx.x * 4 + wv;          // grid 8192
  const float* x = hs + (size_t)t * GD;
  float v[12];
  float s = 0.f, sq = 0.f;
#pragma unroll
  for (int c = 0; c < 3; ++c) {
    float4 u = *(const float4*)(x + c * 256 + ln * 4);
    v[c*4+0] = u.x; v[c*4+1] = u.y; v[c*4+2] = u.z; v[c*4+3] = u.w;
    s  += u.x + u.y + u.z + u.w;
    sq += u.x*u.x + u.y*u.y + u.z*u.z + u.w*u.w;
  }
#pragma unroll
  for (int d = 1; d < 64; d <<= 1) { s += __shfl_xor(s, d); sq += __shfl_xor(sq, d); }
  const float mu = s * (1.f / 768.f);
  const float rstd = rsqrtf(sq * (1.f / 768.f) - mu * mu + 1e-5f);
  const int p = getProp(prop, t, *flag);
  const float* gp = g + (size_t)p * GD;
  const float* bp = bta + (size_t)p * GD;
  u16* yp = y + (size_t)t * GD;
#pragma unroll
  for (int c = 0; c < 3; ++c) {
    float4 ug = *(const float4*)(gp + c * 256 + ln * 4);
    float4 ub = *(const float4*)(bp + c * 256 + ln * 4);
    float y0 = (v[c*4+0] - mu) * rstd * ug.x + ub.x;
    float y1 = (v[c*4+1] - mu) * rstd * ug.y + ub.y;
    float y2 = (v[c*4+2] - mu) * rstd * ug.z + ub.z;
    float y3 = (v[c*4+3] - mu) * rstd * ug.w + ub.w;
    uint2 o;
    o.x = (u32)f2bf(y0) | ((u32)f2bf(y1) << 16);
    o.y = (u32)f2bf(y2) | ((u32)f2bf(y3) << 16);
    *(uint2*)(yp + c * 256 + ln * 4) = o;
  }
}

// ---------------- K3: scan + tile table (1 wave) ----------------
__global__ void scan_kernel(const int* __restrict__ counts_p, int* __restrict__ offsets,
                            int* __restrict__ tileHead, int* __restrict__ tileRow,
                            int* __restrict__ nTilesPtr) {
  const int e = threadIdx.x;  // 0..63
  int c = counts_p[e * 16];
  int inc = c;
#pragma unroll
  for (int d = 1; d < 64; d <<= 1) { int n = __shfl_up(inc, d); if (e >= d) inc += n; }
  const int off = inc - c;
  offsets[e] = off;
  if (e == 63) offsets[64] = inc;
  int ntile = (c + 127) >> 7;
  int inct = ntile;
#pragma unroll
  for (int d = 1; d < 64; d <<= 1) { int n = __shfl_up(inct, d); if (e >= d) inct += n; }
  const int tb = inct - ntile;
  for (int j = 0; j < ntile; ++j) { tileHead[tb + j] = e; tileRow[tb + j] = off + j * 128; }
  if (e == 63) *nTilesPtr = inct;
}

// ---------------- K4: two-phase block scatter (LDS rank + padded cursors) -----
__global__ void scatter_kernel(const int* __restrict__ prop, const float* __restrict__ mask,
                               const int* __restrict__ offsets, int* __restrict__ cursors_p,
                               int* __restrict__ tokenIds, const int* __restrict__ flag) {
  __shared__ int h[GE];
  __shared__ int basebin[GE];
  const int tid = threadIdx.x;
  const int t = blockIdx.x * 256 + tid;  // grid 128
  if (tid < GE) h[tid] = 0;
  __syncthreads();
  int p = -1, rank = 0;
  if (mask[t] > 0.f) {
    p = getProp(prop, t, *flag);
    rank = atomicAdd(&h[p], 1);
  }
  __syncthreads();
  if (tid < GE && h[tid] > 0) basebin[tid] = atomicAdd(&cursors_p[tid * 16], h[tid]);
  __syncthreads();
  if (p >= 0) tokenIds[offsets[p] + basebin[p] + rank] = t;
}

// ---------------- K5: grouped fused adapter GEMM (54.3 KB LDS) ----------------
__global__ __launch_bounds__(256, 1) void adapter_gemm(
    const u16* __restrict__ y, const u16* __restrict__ w1t, const u16* __restrict__ w2t,
    const float* __restrict__ b1, const float* __restrict__ b2,
    const float* __restrict__ w3, const float* __restrict__ b3,
    const float* __restrict__ base, const float* __restrict__ mask,
    const int* __restrict__ tokenIds, const int* __restrict__ offsets,
    const int* __restrict__ tileHead, const int* __restrict__ tileRow,
    const int* __restrict__ nTilesPtr, float* __restrict__ outp) {
  __shared__ u16 sA[128 * 32];     //  8 KB   y k-tile [row][32]
  __shared__ u16 sH[128 * 136];    // 34 KB   h1-half / h2 (aliased), stride 136
  __shared__ u16 sB[128 * 32];     //  8 KB   B k-tile [n][32]
  __shared__ float sBias1[256];
  __shared__ float sBias2[128];
  __shared__ float sW3[2][128];
  __shared__ float sB3[2];
  __shared__ int   sTok[128];

  const int tid  = threadIdx.x;
  const int wv   = tid >> 6;
  const int l15  = tid & 15;
  const int quad = (tid & 63) >> 4;
  const int arow = tid >> 2;            // 0..63
  const int koff = (tid & 3) * 8;       // elements: 0,8,16,24
  const f32x4 vzero = {0.f, 0.f, 0.f, 0.f};
  const int nt = *nTilesPtr;

  for (int tile = blockIdx.x; tile < nt; tile += gridDim.x) {
    __syncthreads();  // protect LDS/meta reuse across tiles
    const int e  = tileHead[tile];
    const int rs = tileRow[tile];
    const int nRows = min(128, offsets[e + 1] - rs);

    if (tid < 128) sTok[tid] = tokenIds[rs + min(tid, nRows - 1)];
    sBias1[tid] = b1[e * GH + tid];
    if (tid < 128) sBias2[tid] = b2[e * GH2 + tid];
    { const int k = tid >> 1, o = tid & 1; sW3[o][k] = w3[e * GH2 * 2 + k * 2 + o]; }
    if (tid < 2) sB3[tid] = b3[e * 2 + tid];
    __syncthreads();

    const u16* yrow0 = y + (size_t)sTok[arow] * GD;
    const u16* yrow1 = y + (size_t)sTok[64 + arow] * GD;
    const u16* w1e = w1t + (size_t)e * GH * GD;
    const u16* w2e = w2t + (size_t)e * GH2 * GH;

    f32x4 acc2[8][2];     // GEMM2 result: 128 rows x 128 cols (wave: 32 cols)
#pragma unroll
    for (int f = 0; f < 8; ++f)
#pragma unroll
      for (int g = 0; g < 2; ++g) acc2[f][g] = vzero;

    // -------- two phases over the H=256 hidden dim (128 cols each) --------
    for (int c = 0; c < 2; ++c) {
      // ---- GEMM1 half: y[128x768] @ W1[768, c*128..c*128+127] ----
      f32x4 acc1[8][2];
#pragma unroll
      for (int f = 0; f < 8; ++f)
#pragma unroll
        for (int g = 0; g < 2; ++g) acc1[f][g] = vzero;

      for (int kt = 0; kt < 24; ++kt) {
        const int k0 = kt * 32;
        async16(sA + wv * 512,        yrow0 + k0 + koff);
        async16(sA + 2048 + wv * 512, yrow1 + k0 + koff);
#pragma unroll
        for (int j = 0; j < 2; ++j)
          async16(sB + j * 2048 + wv * 512,
                  w1e + (size_t)(c * 128 + j * 64 + arow) * GD + k0 + koff);
        __syncthreads();

        Frag fa[8], fb[2];
#pragma unroll
        for (int f = 0; f < 8; ++f)
          fa[f].u = *(const uint4*)&sA[(f * 16 + l15) * 32 + quad * 8];
#pragma unroll
        for (int g = 0; g < 2; ++g)
          fb[g].u = *(const uint4*)&sB[(wv * 32 + g * 16 + l15) * 32 + quad * 8];
#pragma unroll
        for (int f = 0; f < 8; ++f)
#pragma unroll
          for (int g = 0; g < 2; ++g)
            acc1[f][g] = __builtin_amdgcn_mfma_f32_16x16x32_bf16(fa[f].b, fb[g].b, acc1[f][g], 0, 0, 0);
        __syncthreads();
      }

      // epilogue 1: +b1, relu -> sH (local cols 0..127 of this half)
#pragma unroll
      for (int f = 0; f < 8; ++f)
#pragma unroll
        for (int g = 0; g < 2; ++g) {
          const int col = wv * 32 + g * 16 + l15;
          const float bias = sBias1[c * 128 + col];
#pragma unroll
          for (int r = 0; r < 4; ++r) {
            const int row = f * 16 + quad * 4 + r;
            sH[row * 136 + col] = f2bf(fmaxf(acc1[f][g][r] + bias, 0.f));
          }
        }
      __syncthreads();

      // ---- GEMM2 partial: h1half[128x128] @ W2[c*128..+127, 0..127] ----
      for (int kt = 0; kt < 4; ++kt) {
        const int k0 = kt * 32;
#pragma unroll
        for (int j = 0; j < 2; ++j)
          async16(sB + j * 2048 + wv * 512,
                  w2e + (size_t)(j * 64 + arow) * GH + c * 128 + k0 + koff);
        __syncthreads();

        Frag fa2[8], fb2[2];
#pragma unroll
        for (int f = 0; f < 8; ++f)
          fa2[f].u = *(const uint4*)&sH[(f * 16 + l15) * 136 + k0 + quad * 8];
#pragma unroll
        for (int g = 0; g < 2; ++g)
          fb2[g].u = *(const uint4*)&sB[(wv * 32 + g * 16 + l15) * 32 + quad * 8];
#pragma unroll
        for (int f = 0; f < 8; ++f)
#pragma unroll
          for (int g = 0; g < 2; ++g)
            acc2[f][g] = __builtin_amdgcn_mfma_f32_16x16x32_bf16(fa2[f].b, fb2[g].b, acc2[f][g], 0, 0, 0);
        __syncthreads();
      }
    }

    // epilogue 2: +b2, relu -> sH (now h2, 128x128)
#pragma unroll
    for (int f = 0; f < 8; ++f)
#pragma unroll
      for (int g = 0; g < 2; ++g) {
        const int col = wv * 32 + g * 16 + l15;
        const float bias = sBias2[col];
#pragma unroll
        for (int r = 0; r < 4; ++r) {
          const int row = f * 16 + quad * 4 + r;
          sH[row * 136 + col] = f2bf(fmaxf(acc2[f][g][r] + bias, 0.f));
        }
      }
    __syncthreads();

    // ---------- GEMM3 + residual + mask + scatter-store (fp32) ----------
    const int m = tid >> 1, o = tid & 1;
    if (m < nRows) {
      float a = sB3[o];
      const u16* h2row = &sH[m * 136];
#pragma unroll 16
      for (int k = 0; k < 128; ++k) a += bf2f(h2row[k]) * sW3[o][k];
      const int t = sTok[m];
      const float mk = mask[t];
      const float bs = base[t * 2 + o];
      outp[t * 2 + o] = (0.7f * a + 0.3f * bs) * mk;
    }
  }
}

extern "C" void kernel_launch(void* const* d_in, const int* in_sizes, int n_in,
                              void* d_out, int out_size, void* d_ws, size_t ws_size,
                              hipStream_t stream) {
  const float* hs   = (const float*)d_in[0];
  const float* base = (const float*)d_in[1];
  const int*   prop = (const int*)d_in[2];
  const float* mask = (const float*)d_in[3];
  const float* lng  = (const float*)d_in[4];
  const float* lnb  = (const float*)d_in[5];
  const float* W1   = (const float*)d_in[6];
  const float* b1   = (const float*)d_in[7];
  const float* W2   = (const float*)d_in[8];
  const float* b2   = (const float*)d_in[9];
  const float* W3   = (const float*)d_in[10];
  const float* b3   = (const float*)d_in[11];

  char* ws = (char*)d_ws;
  u16* y    = (u16*)(ws + OFF_Y);
  u16* w1t  = (u16*)(ws + OFF_W1T);
  u16* w2t  = (u16*)(ws + OFF_W2T);
  int* tok  = (int*)(ws + OFF_TOK);
  int* meta = (int*)(ws + OFF_META);
  int* counts_p  = meta;          // 1024 ints (64 bins, 64B-padded)
  int* cursors_p = meta + 1024;   // 1024 ints
  int* offsets   = meta + 2048;   // 65 ints
  int* tileHead  = meta + 2176;   // 512 ints
  int* tileRow   = meta + 2688;   // 512 ints
  int* nTiles    = meta + 3200;
  int* propFlag  = meta + 3201;

  prep_kernel<<<256, 256, 0, stream>>>((u32*)d_out, meta);
  prop_probe<<<1, 64, 0, stream>>>(prop, propFlag);
  hist_kernel<<<NTOK / 256, 256, 0, stream>>>(prop, mask, counts_p, propFlag);
  transpose_w1<<<768, 256, 0, stream>>>(W1, w1t);
  transpose_kernel<<<64 * 8 * 4, 256, 0, stream>>>(W2, w2t, GH, GH2, 4);
  ln_kernel<<<NTOK / 4, 256, 0, stream>>>(hs, lng, lnb, prop, y, propFlag);
  scan_kernel<<<1, 64, 0, stream>>>(counts_p, offsets, tileHead, tileRow, nTiles);
  scatter_kernel<<<NTOK / 256, 256, 0, stream>>>(prop, mask, offsets, cursors_p, tok, propFlag);
  adapter_gemm<<<256, 256, 0, stream>>>(y, w1t, w2t, b1, b2, W3, b3, base, mask,
                                        tok, offsets, tileHead, tileRow, nTiles,
                                        (float*)d_out);
}

// Round 4
// 284.792 us; speedup vs baseline: 1.4996x; 1.0110x over previous
//
#include <hip/hip_runtime.h>
#include <stdint.h>

typedef unsigned short u16;
typedef unsigned int   u32;

#define NTOK   32768      // B*P
#define GD     768
#define GH     256
#define GH2    128
#define GE     64

typedef __bf16 bf16x8 __attribute__((ext_vector_type(8)));
typedef float  f32x4  __attribute__((ext_vector_type(4)));
union Frag { uint4 u; bf16x8 b; };

__device__ __forceinline__ float bf2f(u16 h) {
  union { u32 u; float f; } v; v.u = ((u32)h) << 16; return v.f;
}
__device__ __forceinline__ u16 f2bf(float f) {
  union { float f; u32 u; } v; v.f = f;
  u32 r = (v.u + 0x7fffu + ((v.u >> 16) & 1u)) >> 16;
  return (u16)r;
}

__device__ __forceinline__ void async16(void* lds, const void* g) {
  __builtin_amdgcn_global_load_lds(
      (const __attribute__((address_space(1))) void*)g,
      (__attribute__((address_space(3))) void*)lds, 16, 0, 0);
}

__device__ __forceinline__ int getProp(const int* p32, int t, int is64) {
  return is64 ? p32[2 * t] : p32[t];
}

// ---------------- workspace layout (bytes) ----------------
static const size_t OFF_Y    = 0;            // bf16 NTOK*768*2 = 50331648
static const size_t OFF_W1T  = 50331648;     // bf16 64*256*768*2 = 25165824
static const size_t OFF_W2T  = 75497472;     // bf16 64*128*256*2 = 4194304
static const size_t OFF_TOK  = 79691776;     // int  NTOK*4
static const size_t OFF_META = 79822848;     // ints (48 KB)
// meta ints: counts2d[128*64]@0, offsets[65]@8192, tileHead[512]@8320,
//   tileRow[512]@8832, nTiles@9344, flag@9345, cursors_p[1024]@10240

// ---------------- K0: zero out + prop-dtype flag + per-block histogram -------
__global__ void setup_kernel(const int* __restrict__ prop, const float* __restrict__ mask,
                             u32* __restrict__ outz, int* __restrict__ counts2d,
                             int* __restrict__ cursors_p, int* __restrict__ flagp) {
  __shared__ int h[GE];
  __shared__ int vOr;
  const int b = blockIdx.x;                 // grid 128
  const int tid = threadIdx.x;
  // zero d_out (65536 u32) and cursors
  outz[b * 512 + tid] = 0u;
  outz[b * 512 + 256 + tid] = 0u;
  if (b < 4) cursors_p[b * 256 + tid] = 0;
  if (tid < GE) h[tid] = 0;
  if (tid == 0) vOr = 0;
  __syncthreads();
  // every block reads the SAME first 1024 ints (int32-safe) -> identical flag
  int v = prop[2 * tid + 1] | prop[2 * (tid + 256) + 1];
  if (v) atomicOr(&vOr, 1);
  __syncthreads();
  const int is64 = (vOr == 0) ? 1 : 0;
  if (b == 0 && tid == 0) *flagp = is64;
  const int t = b * 256 + tid;
  if (mask[t] > 0.f) atomicAdd(&h[getProp(prop, t, is64)], 1);
  __syncthreads();
  if (tid < GE) counts2d[b * GE + tid] = h[tid];   // unconditional: no zero-init
}

// ---------------- K1a: W1 fp32 [64][768][256] -> bf16 [64][256][768] ----------
__global__ void transpose_w1(const float* __restrict__ in, u16* __restrict__ out) {
  __shared__ u16 tl[64][260];               // [h][d], 33.3 KB
  const int bid = blockIdx.x;               // grid 64*3*4 = 768
  const int e  = bid / 12, r = bid % 12;
  const int d0 = (r / 4) * 256, h0 = (r % 4) * 64;
  const int tid = threadIdx.x;
  const size_t inMat = (size_t)e * GD * GH;
  const size_t outMat = (size_t)e * GH * GD;
  const int h_l = (tid & 15) * 4, d_l = tid >> 4;
#pragma unroll
  for (int dd = 0; dd < 16; ++dd) {
    const int d = d_l + dd * 16;
    float4 v = *(const float4*)(in + inMat + (size_t)(d0 + d) * GH + h0 + h_l);
    tl[h_l + 0][d] = f2bf(v.x);
    tl[h_l + 1][d] = f2bf(v.y);
    tl[h_l + 2][d] = f2bf(v.z);
    tl[h_l + 3][d] = f2bf(v.w);
  }
  __syncthreads();
  const int wv = tid >> 6, ln = tid & 63;
#pragma unroll
  for (int hh = 0; hh < 16; ++hh) {
    const int h = wv * 16 + hh;
    *(uint2*)(out + outMat + (size_t)(h0 + h) * GD + d0 + ln * 4) =
        *(const uint2*)&tl[h][ln * 4];
  }
}

// ---------------- K1b: generic fp32 [E][R][C] -> bf16 [E][C][R] (W2) ----------
__global__ void transpose_kernel(const float* __restrict__ in, u16* __restrict__ out,
                                 int R, int C, int tilesC) {
  __shared__ u16 tile[32][33];
  const int tilesPerMat = (R >> 5) * tilesC;
  const int e  = blockIdx.x / tilesPerMat;
  const int t  = blockIdx.x % tilesPerMat;
  const int tr = t / tilesC, tc = t % tilesC;
  const size_t mat = (size_t)e * R * C;
  const int tx = threadIdx.x & 31, ty = threadIdx.x >> 5;
  const int r0 = tr * 32, c0 = tc * 32;
#pragma unroll
  for (int i = 0; i < 32; i += 8)
    tile[ty + i][tx] = f2bf(in[mat + (size_t)(r0 + ty + i) * C + c0 + tx]);
  __syncthreads();
#pragma unroll
  for (int i = 0; i < 32; i += 8)
    out[mat + (size_t)(c0 + ty + i) * R + r0 + tx] = tile[tx][ty + i];
}

// ---------------- K2: LayerNorm -> y bf16 (pure stream) -----------------------
__global__ void ln_kernel(const float* __restrict__ hs, const float* __restrict__ g,
                          const float* __restrict__ bta, const int* __restrict__ prop,
                          u16* __restrict__ y, const int* __restrict__ flag) {
  const int wv = threadIdx.x >> 6, ln = threadIdx.x & 63;
  const int t = blockIdx.x * 4 + wv;          // grid 8192
  const float* x = hs + (size_t)t * GD;
  float v[12];
  float s = 0.f, sq = 0.f;
#pragma unroll
  for (int c = 0; c < 3; ++c) {
    float4 u = *(const float4*)(x + c * 256 + ln * 4);
    v[c*4+0] = u.x; v[c*4+1] = u.y; v[c*4+2] = u.z; v[c*4+3] = u.w;
    s  += u.x + u.y + u.z + u.w;
    sq += u.x*u.x + u.y*u.y + u.z*u.z + u.w*u.w;
  }
#pragma unroll
  for (int d = 1; d < 64; d <<= 1) { s += __shfl_xor(s, d); sq += __shfl_xor(sq, d); }
  const float mu = s * (1.f / 768.f);
  const float rstd = rsqrtf(sq * (1.f / 768.f) - mu * mu + 1e-5f);
  const int p = getProp(prop, t, *flag);
  const float* gp = g + (size_t)p * GD;
  const float* bp = bta + (size_t)p * GD;
  u16* yp = y + (size_t)t * GD;
#pragma unroll
  for (int c = 0; c < 3; ++c) {
    float4 ug = *(const float4*)(gp + c * 256 + ln * 4);
    float4 ub = *(const float4*)(bp + c * 256 + ln * 4);
    float y0 = (v[c*4+0] - mu) * rstd * ug.x + ub.x;
    float y1 = (v[c*4+1] - mu) * rstd * ug.y + ub.y;
    float y2 = (v[c*4+2] - mu) * rstd * ug.z + ub.z;
    float y3 = (v[c*4+3] - mu) * rstd * ug.w + ub.w;
    uint2 o;
    o.x = (u32)f2bf(y0) | ((u32)f2bf(y1) << 16);
    o.y = (u32)f2bf(y2) | ((u32)f2bf(y3) << 16);
    *(uint2*)(yp + c * 256 + ln * 4) = o;
  }
}

// ---------------- K3: reduce counts2d + scan + tile table (1 wave) ------------
__global__ void scan_kernel(const int* __restrict__ counts2d, int* __restrict__ offsets,
                            int* __restrict__ tileHead, int* __restrict__ tileRow,
                            int* __restrict__ nTilesPtr) {
  const int e = threadIdx.x;  // 0..63
  int c = 0;
  for (int b = 0; b < 128; ++b) c += counts2d[b * GE + e];
  int inc = c;
#pragma unroll
  for (int d = 1; d < 64; d <<= 1) { int n = __shfl_up(inc, d); if (e >= d) inc += n; }
  const int off = inc - c;
  offsets[e] = off;
  if (e == 63) offsets[64] = inc;
  int ntile = (c + 127) >> 7;
  int inct = ntile;
#pragma unroll
  for (int d = 1; d < 64; d <<= 1) { int n = __shfl_up(inct, d); if (e >= d) inct += n; }
  const int tb = inct - ntile;
  for (int j = 0; j < ntile; ++j) { tileHead[tb + j] = e; tileRow[tb + j] = off + j * 128; }
  if (e == 63) *nTilesPtr = inct;
}

// ---------------- K4: two-phase block scatter ---------------------------------
__global__ void scatter_kernel(const int* __restrict__ prop, const float* __restrict__ mask,
                               const int* __restrict__ offsets, int* __restrict__ cursors_p,
                               int* __restrict__ tokenIds, const int* __restrict__ flag) {
  __shared__ int h[GE];
  __shared__ int basebin[GE];
  const int tid = threadIdx.x;
  const int t = blockIdx.x * 256 + tid;  // grid 128
  if (tid < GE) h[tid] = 0;
  __syncthreads();
  int p = -1, rank = 0;
  if (mask[t] > 0.f) {
    p = getProp(prop, t, *flag);
    rank = atomicAdd(&h[p], 1);
  }
  __syncthreads();
  if (tid < GE && h[tid] > 0) basebin[tid] = atomicAdd(&cursors_p[tid * 16], h[tid]);
  __syncthreads();
  if (p >= 0) tokenIds[offsets[p] + basebin[p] + rank] = t;
}

// ---------------- K5: grouped fused adapter GEMM (pipelined, ~53 KB LDS) ------
__global__ __launch_bounds__(256, 2) void adapter_gemm(
    const u16* __restrict__ y, const u16* __restrict__ w1t, const u16* __restrict__ w2t,
    const float* __restrict__ b1, const float* __restrict__ b2,
    const float* __restrict__ w3, const float* __restrict__ b3,
    const float* __restrict__ base, const float* __restrict__ mask,
    const int* __restrict__ tokenIds, const int* __restrict__ offsets,
    const int* __restrict__ tileHead, const int* __restrict__ tileRow,
    const int* __restrict__ nTilesPtr, float* __restrict__ outp) {
  // GEMM1 staging (4x8KB dbuf) aliased with sH (h1-half / h2, stride 136)
  __shared__ union LU {
    u16 g1[4][4096];    // [sA0, sA1, sB0, sB1], 32 KB
    u16 h[17408];       // 128 x 136, 34 KB
  } uni;
  __shared__ u16 sB2[2][4096];   // GEMM2 B dbuf, 16 KB
  __shared__ float sBias1[256];
  __shared__ float sBias2[128];
  __shared__ float sW3[2][128];
  __shared__ float sB3[2];
  __shared__ int   sTok[128];

  const int tid  = threadIdx.x;
  const int wv   = tid >> 6;
  const int l15  = tid & 15;
  const int quad = (tid & 63) >> 4;
  const int arow = tid >> 2;            // 0..63
  const int koff = (tid & 3) * 8;       // elements: 0,8,16,24
  const f32x4 vzero = {0.f, 0.f, 0.f, 0.f};
  const int nt = *nTilesPtr;

  for (int tile = blockIdx.x; tile < nt; tile += gridDim.x) {
    __syncthreads();  // protect LDS/meta reuse across tiles
    const int e  = tileHead[tile];
    const int rs = tileRow[tile];
    const int nRows = min(128, offsets[e + 1] - rs);

    if (tid < 128) sTok[tid] = tokenIds[rs + min(tid, nRows - 1)];
    sBias1[tid] = b1[e * GH + tid];
    if (tid < 128) sBias2[tid] = b2[e * GH2 + tid];
    { const int k = tid >> 1, o = tid & 1; sW3[o][k] = w3[e * GH2 * 2 + k * 2 + o]; }
    if (tid < 2) sB3[tid] = b3[e * 2 + tid];
    __syncthreads();

    const u16* yrow0 = y + (size_t)sTok[arow] * GD;
    const u16* yrow1 = y + (size_t)sTok[64 + arow] * GD;
    const u16* w1e = w1t + (size_t)e * GH * GD;
    const u16* w2e = w2t + (size_t)e * GH2 * GH;

    f32x4 acc2[8][2];
#pragma unroll
    for (int f = 0; f < 8; ++f)
#pragma unroll
      for (int g = 0; g < 2; ++g) acc2[f][g] = vzero;

    for (int c = 0; c < 2; ++c) {
      f32x4 acc1[8][2];
#pragma unroll
      for (int f = 0; f < 8; ++f)
#pragma unroll
        for (int g = 0; g < 2; ++g) acc1[f][g] = vzero;

      // prefetch kt=0 into buffer 0 (uni region is free here)
      {
        u16* a = uni.g1[0]; u16* bb = uni.g1[2];
        async16(a + wv * 512,        yrow0 + koff);
        async16(a + 2048 + wv * 512, yrow1 + koff);
#pragma unroll
        for (int j = 0; j < 2; ++j)
          async16(bb + j * 2048 + wv * 512,
                  w1e + (size_t)(c * 128 + j * 64 + arow) * GD + koff);
      }

      // ---- GEMM1 half: pipelined, 1 barrier per k-step ----
      for (int kt = 0; kt < 24; ++kt) {
        __syncthreads();   // drains kt's loads (issued one iter ago) + LDS reuse
        if (kt + 1 < 24) {
          const int k0 = (kt + 1) * 32;
          const int par = (kt + 1) & 1;
          u16* a = uni.g1[par]; u16* bb = uni.g1[2 + par];
          async16(a + wv * 512,        yrow0 + k0 + koff);
          async16(a + 2048 + wv * 512, yrow1 + k0 + koff);
#pragma unroll
          for (int j = 0; j < 2; ++j)
            async16(bb + j * 2048 + wv * 512,
                    w1e + (size_t)(c * 128 + j * 64 + arow) * GD + k0 + koff);
        }
        const int par = kt & 1;
        const u16* a = uni.g1[par]; const u16* bb = uni.g1[2 + par];
        Frag fa[8], fb[2];
#pragma unroll
        for (int f = 0; f < 8; ++f)
          fa[f].u = *(const uint4*)&a[(f * 16 + l15) * 32 + quad * 8];
#pragma unroll
        for (int g = 0; g < 2; ++g)
          fb[g].u = *(const uint4*)&bb[(wv * 32 + g * 16 + l15) * 32 + quad * 8];
#pragma unroll
        for (int f = 0; f < 8; ++f)
#pragma unroll
          for (int g = 0; g < 2; ++g)
            acc1[f][g] = __builtin_amdgcn_mfma_f32_16x16x32_bf16(fa[f].b, fb[g].b, acc1[f][g], 0, 0, 0);
      }
      __syncthreads();   // all reads of g1 bufs done -> uni.h writable

      // prefetch GEMM2 B kt=0 (separate region; overlaps epilogue VALU)
#pragma unroll
      for (int j = 0; j < 2; ++j)
        async16(sB2[0] + j * 2048 + wv * 512,
                w2e + (size_t)(j * 64 + arow) * GH + c * 128 + koff);

      // epilogue 1: +b1, relu -> uni.h (local cols 0..127 of this half)
#pragma unroll
      for (int f = 0; f < 8; ++f)
#pragma unroll
        for (int g = 0; g < 2; ++g) {
          const int col = wv * 32 + g * 16 + l15;
          const float bias = sBias1[c * 128 + col];
#pragma unroll
          for (int r = 0; r < 4; ++r) {
            const int row = f * 16 + quad * 4 + r;
            uni.h[row * 136 + col] = f2bf(fmaxf(acc1[f][g][r] + bias, 0.f));
          }
        }

      // ---- GEMM2 partial: pipelined ----
      for (int kt = 0; kt < 4; ++kt) {
        __syncthreads();
        if (kt + 1 < 4) {
          const int k0 = (kt + 1) * 32;
          const int par = (kt + 1) & 1;
#pragma unroll
          for (int j = 0; j < 2; ++j)
            async16(sB2[par] + j * 2048 + wv * 512,
                    w2e + (size_t)(j * 64 + arow) * GH + c * 128 + k0 + koff);
        }
        const int par = kt & 1;
        Frag fa2[8], fb2[2];
#pragma unroll
        for (int f = 0; f < 8; ++f)
          fa2[f].u = *(const uint4*)&uni.h[(f * 16 + l15) * 136 + kt * 32 + quad * 8];
#pragma unroll
        for (int g = 0; g < 2; ++g)
          fb2[g].u = *(const uint4*)&sB2[par][(wv * 32 + g * 16 + l15) * 32 + quad * 8];
#pragma unroll
        for (int f = 0; f < 8; ++f)
#pragma unroll
          for (int g = 0; g < 2; ++g)
            acc2[f][g] = __builtin_amdgcn_mfma_f32_16x16x32_bf16(fa2[f].b, fb2[g].b, acc2[f][g], 0, 0, 0);
      }
      __syncthreads();   // uni region free for next phase / epilogue2
    }

    // epilogue 2: +b2, relu -> uni.h (now h2, 128x128)
#pragma unroll
    for (int f = 0; f < 8; ++f)
#pragma unroll
      for (int g = 0; g < 2; ++g) {
        const int col = wv * 32 + g * 16 + l15;
        const float bias = sBias2[col];
#pragma unroll
        for (int r = 0; r < 4; ++r) {
          const int row = f * 16 + quad * 4 + r;
          uni.h[row * 136 + col] = f2bf(fmaxf(acc2[f][g][r] + bias, 0.f));
        }
      }
    __syncthreads();

    // ---------- GEMM3 + residual + mask + scatter-store (fp32) ----------
    const int m = tid >> 1, o = tid & 1;
    if (m < nRows) {
      float a = sB3[o];
      const u16* h2row = &uni.h[m * 136];
#pragma unroll 16
      for (int k = 0; k < 128; ++k) a += bf2f(h2row[k]) * sW3[o][k];
      const int t = sTok[m];
      const float mk = mask[t];
      const float bs = base[t * 2 + o];
      outp[t * 2 + o] = (0.7f * a + 0.3f * bs) * mk;
    }
  }
}

extern "C" void kernel_launch(void* const* d_in, const int* in_sizes, int n_in,
                              void* d_out, int out_size, void* d_ws, size_t ws_size,
                              hipStream_t stream) {
  const float* hs   = (const float*)d_in[0];
  const float* base = (const float*)d_in[1];
  const int*   prop = (const int*)d_in[2];
  const float* mask = (const float*)d_in[3];
  const float* lng  = (const float*)d_in[4];
  const float* lnb  = (const float*)d_in[5];
  const float* W1   = (const float*)d_in[6];
  const float* b1   = (const float*)d_in[7];
  const float* W2   = (const float*)d_in[8];
  const float* b2   = (const float*)d_in[9];
  const float* W3   = (const float*)d_in[10];
  const float* b3   = (const float*)d_in[11];

  char* ws = (char*)d_ws;
  u16* y    = (u16*)(ws + OFF_Y);
  u16* w1t  = (u16*)(ws + OFF_W1T);
  u16* w2t  = (u16*)(ws + OFF_W2T);
  int* tok  = (int*)(ws + OFF_TOK);
  int* meta = (int*)(ws + OFF_META);
  int* counts2d  = meta;          // 8192 ints
  int* offsets   = meta + 8192;   // 65 ints
  int* tileHead  = meta + 8320;   // 512 ints
  int* tileRow   = meta + 8832;   // 512 ints
  int* nTiles    = meta + 9344;
  int* propFlag  = meta + 9345;
  int* cursors_p = meta + 10240;  // 1024 ints (64 bins, 64B-padded)

  setup_kernel<<<128, 256, 0, stream>>>(prop, mask, (u32*)d_out, counts2d,
                                        cursors_p, propFlag);
  transpose_w1<<<768, 256, 0, stream>>>(W1, w1t);
  transpose_kernel<<<64 * 8 * 4, 256, 0, stream>>>(W2, w2t, GH, GH2, 4);
  ln_kernel<<<NTOK / 4, 256, 0, stream>>>(hs, lng, lnb, prop, y, propFlag);
  scan_kernel<<<1, 64, 0, stream>>>(counts2d, offsets, tileHead, tileRow, nTiles);
  scatter_kernel<<<NTOK / 256, 256, 0, stream>>>(prop, mask, offsets, cursors_p, tok, propFlag);
  adapter_gemm<<<512, 256, 0, stream>>>(y, w1t, w2t, b1, b2, W3, b3, base, mask,
                                        tok, offsets, tileHead, tileRow, nTiles,
                                        (float*)d_out);
}

// Round 5
// 283.009 us; speedup vs baseline: 1.5091x; 1.0063x over previous
//
#include <hip/hip_runtime.h>
#include <stdint.h>

typedef unsigned short u16;
typedef unsigned int   u32;

#define NTOK   32768      // B*P
#define GD     768
#define GH     256
#define GH2    128
#define GE     64

typedef __bf16 bf16x8 __attribute__((ext_vector_type(8)));
typedef float  f32x4  __attribute__((ext_vector_type(4)));
union Frag { uint4 u; bf16x8 b; };

__device__ __forceinline__ float bf2f(u16 h) {
  union { u32 u; float f; } v; v.u = ((u32)h) << 16; return v.f;
}
__device__ __forceinline__ u16 f2bf(float f) {
  union { float f; u32 u; } v; v.f = f;
  u32 r = (v.u + 0x7fffu + ((v.u >> 16) & 1u)) >> 16;
  return (u16)r;
}

__device__ __forceinline__ void async16(void* lds, const void* g) {
  __builtin_amdgcn_global_load_lds(
      (const __attribute__((address_space(1))) void*)g,
      (__attribute__((address_space(3))) void*)lds, 16, 0, 0);
}

__device__ __forceinline__ int getProp(const int* p32, int t, int is64) {
  return is64 ? p32[2 * t] : p32[t];
}

// ---------------- workspace layout (bytes) ----------------
static const size_t OFF_Y    = 0;            // bf16 NTOK*768*2 = 50331648
static const size_t OFF_W1T  = 50331648;     // bf16 64*256*768*2 = 25165824
static const size_t OFF_W2T  = 75497472;     // bf16 64*128*256*2 = 4194304
static const size_t OFF_TOK  = 79691776;     // int  NTOK*4
static const size_t OFF_META = 79822848;     // ints (~46 KB)
// meta ints: counts2d[8192]@0, offsets[65]@8192, tileHead[1024]@8320,
//   tileRow[1024]@9344, nTiles@10368, flag@10369, cursors_p[1024]@10432

// ---------------- K0: zero out + prop-dtype flag + per-block histogram -------
__global__ void setup_kernel(const int* __restrict__ prop, const float* __restrict__ mask,
                             u32* __restrict__ outz, int* __restrict__ counts2d,
                             int* __restrict__ cursors_p, int* __restrict__ flagp) {
  __shared__ int h[GE];
  __shared__ int vOr;
  const int b = blockIdx.x;                 // grid 128
  const int tid = threadIdx.x;
  outz[b * 512 + tid] = 0u;
  outz[b * 512 + 256 + tid] = 0u;
  if (b < 4) cursors_p[b * 256 + tid] = 0;
  if (tid < GE) h[tid] = 0;
  if (tid == 0) vOr = 0;
  __syncthreads();
  int v = prop[2 * tid + 1] | prop[2 * (tid + 256) + 1];
  if (v) atomicOr(&vOr, 1);
  __syncthreads();
  const int is64 = (vOr == 0) ? 1 : 0;
  if (b == 0 && tid == 0) *flagp = is64;
  const int t = b * 256 + tid;
  if (mask[t] > 0.f) atomicAdd(&h[getProp(prop, t, is64)], 1);
  __syncthreads();
  if (tid < GE) counts2d[b * GE + tid] = h[tid];
}

// ---------------- K1a: W1 fp32 [64][768][256] -> bf16 [64][256][768] ----------
__global__ void transpose_w1(const float* __restrict__ in, u16* __restrict__ out) {
  __shared__ u16 tl[64][260];               // [h][d], 33.3 KB
  const int bid = blockIdx.x;               // grid 64*3*4 = 768
  const int e  = bid / 12, r = bid % 12;
  const int d0 = (r / 4) * 256, h0 = (r % 4) * 64;
  const int tid = threadIdx.x;
  const size_t inMat = (size_t)e * GD * GH;
  const size_t outMat = (size_t)e * GH * GD;
  const int h_l = (tid & 15) * 4, d_l = tid >> 4;
#pragma unroll
  for (int dd = 0; dd < 16; ++dd) {
    const int d = d_l + dd * 16;
    float4 v = *(const float4*)(in + inMat + (size_t)(d0 + d) * GH + h0 + h_l);
    tl[h_l + 0][d] = f2bf(v.x);
    tl[h_l + 1][d] = f2bf(v.y);
    tl[h_l + 2][d] = f2bf(v.z);
    tl[h_l + 3][d] = f2bf(v.w);
  }
  __syncthreads();
  const int wv = tid >> 6, ln = tid & 63;
#pragma unroll
  for (int hh = 0; hh < 16; ++hh) {
    const int h = wv * 16 + hh;
    *(uint2*)(out + outMat + (size_t)(h0 + h) * GD + d0 + ln * 4) =
        *(const uint2*)&tl[h][ln * 4];
  }
}

// ---------------- K1b: generic fp32 [E][R][C] -> bf16 [E][C][R] (W2) ----------
__global__ void transpose_kernel(const float* __restrict__ in, u16* __restrict__ out,
                                 int R, int C, int tilesC) {
  __shared__ u16 tile[32][33];
  const int tilesPerMat = (R >> 5) * tilesC;
  const int e  = blockIdx.x / tilesPerMat;
  const int t  = blockIdx.x % tilesPerMat;
  const int tr = t / tilesC, tc = t % tilesC;
  const size_t mat = (size_t)e * R * C;
  const int tx = threadIdx.x & 31, ty = threadIdx.x >> 5;
  const int r0 = tr * 32, c0 = tc * 32;
#pragma unroll
  for (int i = 0; i < 32; i += 8)
    tile[ty + i][tx] = f2bf(in[mat + (size_t)(r0 + ty + i) * C + c0 + tx]);
  __syncthreads();
#pragma unroll
  for (int i = 0; i < 32; i += 8)
    out[mat + (size_t)(c0 + ty + i) * R + r0 + tx] = tile[tx][ty + i];
}

// ---------------- K2: LayerNorm -> y bf16 (pure stream) -----------------------
__global__ void ln_kernel(const float* __restrict__ hs, const float* __restrict__ g,
                          const float* __restrict__ bta, const int* __restrict__ prop,
                          u16* __restrict__ y, const int* __restrict__ flag) {
  const int wv = threadIdx.x >> 6, ln = threadIdx.x & 63;
  const int t = blockIdx.x * 4 + wv;          // grid 8192
  const float* x = hs + (size_t)t * GD;
  float v[12];
  float s = 0.f, sq = 0.f;
#pragma unroll
  for (int c = 0; c < 3; ++c) {
    float4 u = *(const float4*)(x + c * 256 + ln * 4);
    v[c*4+0] = u.x; v[c*4+1] = u.y; v[c*4+2] = u.z; v[c*4+3] = u.w;
    s  += u.x + u.y + u.z + u.w;
    sq += u.x*u.x + u.y*u.y + u.z*u.z + u.w*u.w;
  }
#pragma unroll
  for (int d = 1; d < 64; d <<= 1) { s += __shfl_xor(s, d); sq += __shfl_xor(sq, d); }
  const float mu = s * (1.f / 768.f);
  const float rstd = rsqrtf(sq * (1.f / 768.f) - mu * mu + 1e-5f);
  const int p = getProp(prop, t, *flag);
  const float* gp = g + (size_t)p * GD;
  const float* bp = bta + (size_t)p * GD;
  u16* yp = y + (size_t)t * GD;
#pragma unroll
  for (int c = 0; c < 3; ++c) {
    float4 ug = *(const float4*)(gp + c * 256 + ln * 4);
    float4 ub = *(const float4*)(bp + c * 256 + ln * 4);
    float y0 = (v[c*4+0] - mu) * rstd * ug.x + ub.x;
    float y1 = (v[c*4+1] - mu) * rstd * ug.y + ub.y;
    float y2 = (v[c*4+2] - mu) * rstd * ug.z + ub.z;
    float y3 = (v[c*4+3] - mu) * rstd * ug.w + ub.w;
    uint2 o;
    o.x = (u32)f2bf(y0) | ((u32)f2bf(y1) << 16);
    o.y = (u32)f2bf(y2) | ((u32)f2bf(y3) << 16);
    *(uint2*)(yp + c * 256 + ln * 4) = o;
  }
}

// ---------------- K3: reduce counts2d + scan + tile table (64-row tiles) ------
__global__ void scan_kernel(const int* __restrict__ counts2d, int* __restrict__ offsets,
                            int* __restrict__ tileHead, int* __restrict__ tileRow,
                            int* __restrict__ nTilesPtr) {
  const int e = threadIdx.x;  // 0..63
  int c = 0;
  for (int b = 0; b < 128; ++b) c += counts2d[b * GE + e];
  int inc = c;
#pragma unroll
  for (int d = 1; d < 64; d <<= 1) { int n = __shfl_up(inc, d); if (e >= d) inc += n; }
  const int off = inc - c;
  offsets[e] = off;
  if (e == 63) offsets[64] = inc;
  int ntile = (c + 63) >> 6;
  int inct = ntile;
#pragma unroll
  for (int d = 1; d < 64; d <<= 1) { int n = __shfl_up(inct, d); if (e >= d) inct += n; }
  const int tb = inct - ntile;
  for (int j = 0; j < ntile; ++j) { tileHead[tb + j] = e; tileRow[tb + j] = off + j * 64; }
  if (e == 63) *nTilesPtr = inct;
}

// ---------------- K4: two-phase block scatter ---------------------------------
__global__ void scatter_kernel(const int* __restrict__ prop, const float* __restrict__ mask,
                               const int* __restrict__ offsets, int* __restrict__ cursors_p,
                               int* __restrict__ tokenIds, const int* __restrict__ flag) {
  __shared__ int h[GE];
  __shared__ int basebin[GE];
  const int tid = threadIdx.x;
  const int t = blockIdx.x * 256 + tid;  // grid 128
  if (tid < GE) h[tid] = 0;
  __syncthreads();
  int p = -1, rank = 0;
  if (mask[t] > 0.f) {
    p = getProp(prop, t, *flag);
    rank = atomicAdd(&h[p], 1);
  }
  __syncthreads();
  if (tid < GE && h[tid] > 0) basebin[tid] = atomicAdd(&cursors_p[tid * 16], h[tid]);
  __syncthreads();
  if (p >= 0) tokenIds[offsets[p] + basebin[p] + rank] = t;
}

// ---------------- K5: grouped fused adapter GEMM -------------------------------
// 64-row x 256-col tiles, single GEMM1 pass, k-group-major LDS staging.
// LDS: union(stage 40KB, h 34KB) + sB2 16KB + misc ~3KB = ~59KB -> 2 blocks/CU.
__global__ __launch_bounds__(256, 2) void adapter_gemm(
    const u16* __restrict__ y, const u16* __restrict__ w1t, const u16* __restrict__ w2t,
    const float* __restrict__ b1, const float* __restrict__ b2,
    const float* __restrict__ w3, const float* __restrict__ b3,
    const float* __restrict__ base, const float* __restrict__ mask,
    const int* __restrict__ tokenIds, const int* __restrict__ offsets,
    const int* __restrict__ tileHead, const int* __restrict__ tileRow,
    const int* __restrict__ nTilesPtr, float* __restrict__ outp) {
  __shared__ union LU {
    struct { u16 A[2][2048]; u16 B[2][8192]; } s;   // staging: [kgrp4][row][8]
    u16 h[17408];                                   // h1 stride 264 / h2 stride 130
  } uni;
  __shared__ u16 sB2[2][4096];   // GEMM2 B staging [kgrp4][n128][8], dbuf
  __shared__ float sBias1[256];
  __shared__ float sBias2[128];
  __shared__ float sW3[2][128];
  __shared__ float sB3[2];
  __shared__ int   sTok[64];

  const int tid  = threadIdx.x;
  const int wv   = tid >> 6;
  const int ln   = tid & 63;
  const int l15  = tid & 15;
  const int quad = (tid & 63) >> 4;
  const f32x4 vzero = {0.f, 0.f, 0.f, 0.f};
  const int nt = *nTilesPtr;

  for (int tile = blockIdx.x; tile < nt; tile += gridDim.x) {
    __syncthreads();  // protect LDS/meta reuse across tiles
    const int e  = tileHead[tile];
    const int rs = tileRow[tile];
    const int nRows = min(64, offsets[e + 1] - rs);

    if (tid < 64) sTok[tid] = tokenIds[rs + min(tid, nRows - 1)];
    sBias1[tid] = b1[e * GH + tid];
    if (tid < 128) sBias2[tid] = b2[e * GH2 + tid];
    { const int k = tid >> 1, o = tid & 1; sW3[o][k] = w3[e * GH2 * 2 + k * 2 + o]; }
    if (tid < 2) sB3[tid] = b3[e * 2 + tid];
    __syncthreads();

    const u16* yrow = y + (size_t)sTok[ln] * GD;       // per-lane row pointer
    const u16* w1e = w1t + (size_t)e * GH * GD;
    const u16* w2e = w2t + (size_t)e * GH2 * GH;

    // ---- GEMM1: y[64x768] @ W1t -> h1[64x256]; 24 k-steps, BK=32 ----
    f32x4 acc1[4][4];
#pragma unroll
    for (int f = 0; f < 4; ++f)
#pragma unroll
      for (int g = 0; g < 4; ++g) acc1[f][g] = vzero;

    // prefetch kt=0: wave wv stages k-group wv (k = k0 + wv*8 .. +7)
    {
      async16(uni.s.A[0] + wv * 512, yrow + wv * 8);
#pragma unroll
      for (int j = 0; j < 4; ++j)
        async16(uni.s.B[0] + wv * 2048 + j * 512,
                w1e + (size_t)(j * 64 + ln) * GD + wv * 8);
    }

    for (int kt = 0; kt < 24; ++kt) {
      __syncthreads();   // drains kt's staging loads (issued one iter ago)
      if (kt + 1 < 24) {
        const int k0 = (kt + 1) * 32;
        const int par = (kt + 1) & 1;
        async16(uni.s.A[par] + wv * 512, yrow + k0 + wv * 8);
#pragma unroll
        for (int j = 0; j < 4; ++j)
          async16(uni.s.B[par] + wv * 2048 + j * 512,
                  w1e + (size_t)(j * 64 + ln) * GD + k0 + wv * 8);
      }
      const int par = kt & 1;
      Frag fa[4], fb[4];
#pragma unroll
      for (int f = 0; f < 4; ++f)
        fa[f].u = *(const uint4*)&uni.s.A[par][quad * 512 + (f * 16 + l15) * 8];
#pragma unroll
      for (int g = 0; g < 4; ++g)
        fb[g].u = *(const uint4*)&uni.s.B[par][quad * 2048 + (wv * 64 + g * 16 + l15) * 8];
#pragma unroll
      for (int f = 0; f < 4; ++f)
#pragma unroll
        for (int g = 0; g < 4; ++g)
          acc1[f][g] = __builtin_amdgcn_mfma_f32_16x16x32_bf16(fa[f].b, fb[g].b, acc1[f][g], 0, 0, 0);
    }
    __syncthreads();   // staging region fully read -> uni.h writable

    // prefetch GEMM2 B kt=0 (separate region; overlaps epilogue VALU)
#pragma unroll
    for (int j = 0; j < 2; ++j)
      async16(sB2[0] + wv * 1024 + j * 512,
              w2e + (size_t)(j * 64 + ln) * GH + wv * 8);

    // epilogue 1: +b1, relu -> uni.h (stride 264)
#pragma unroll
    for (int f = 0; f < 4; ++f)
#pragma unroll
      for (int g = 0; g < 4; ++g) {
        const int col = wv * 64 + g * 16 + l15;
        const float bias = sBias1[col];
#pragma unroll
        for (int r = 0; r < 4; ++r) {
          const int row = f * 16 + quad * 4 + r;
          uni.h[row * 264 + col] = f2bf(fmaxf(acc1[f][g][r] + bias, 0.f));
        }
      }

    // ---- GEMM2: h1[64x256] @ W2t -> 64x128; 8 k-steps ----
    f32x4 acc2[4][2];
#pragma unroll
    for (int f = 0; f < 4; ++f)
#pragma unroll
      for (int g = 0; g < 2; ++g) acc2[f][g] = vzero;

    for (int kt = 0; kt < 8; ++kt) {
      __syncthreads();   // drains kt's sB2 loads; also makes h1 visible (kt=0)
      if (kt + 1 < 8) {
        const int k0 = (kt + 1) * 32;
        const int par = (kt + 1) & 1;
#pragma unroll
        for (int j = 0; j < 2; ++j)
          async16(sB2[par] + wv * 1024 + j * 512,
                  w2e + (size_t)(j * 64 + ln) * GH + k0 + wv * 8);
      }
      const int par = kt & 1;
      Frag fa2[4], fb2[2];
#pragma unroll
      for (int f = 0; f < 4; ++f)
        fa2[f].u = *(const uint4*)&uni.h[(f * 16 + l15) * 264 + kt * 32 + quad * 8];
#pragma unroll
      for (int g = 0; g < 2; ++g)
        fb2[g].u = *(const uint4*)&sB2[par][quad * 1024 + (wv * 32 + g * 16 + l15) * 8];
#pragma unroll
      for (int f = 0; f < 4; ++f)
#pragma unroll
        for (int g = 0; g < 2; ++g)
          acc2[f][g] = __builtin_amdgcn_mfma_f32_16x16x32_bf16(fa2[f].b, fb2[g].b, acc2[f][g], 0, 0, 0);
    }
    __syncthreads();   // h1 reads done -> overwrite with h2

    // epilogue 2: +b2, relu -> uni.h as h2 (stride 130: bank-clean for GEMM3)
#pragma unroll
    for (int f = 0; f < 4; ++f)
#pragma unroll
      for (int g = 0; g < 2; ++g) {
        const int col = wv * 32 + g * 16 + l15;
        const float bias = sBias2[col];
#pragma unroll
        for (int r = 0; r < 4; ++r) {
          const int row = f * 16 + quad * 4 + r;
          uni.h[row * 130 + col] = f2bf(fmaxf(acc2[f][g][r] + bias, 0.f));
        }
      }
    __syncthreads();

    // ---------- GEMM3 + residual + mask + scatter-store (fp32) ----------
    const int m = tid >> 1, o = tid & 1;
    if (m < nRows) {
      float a = sB3[o];
      const u16* h2row = &uni.h[m * 130];
#pragma unroll 16
      for (int k = 0; k < 128; ++k) a += bf2f(h2row[k]) * sW3[o][k];
      const int t = sTok[m];
      const float mk = mask[t];
      const float bs = base[t * 2 + o];
      outp[t * 2 + o] = (0.7f * a + 0.3f * bs) * mk;
    }
  }
}

extern "C" void kernel_launch(void* const* d_in, const int* in_sizes, int n_in,
                              void* d_out, int out_size, void* d_ws, size_t ws_size,
                              hipStream_t stream) {
  const float* hs   = (const float*)d_in[0];
  const float* base = (const float*)d_in[1];
  const int*   prop = (const int*)d_in[2];
  const float* mask = (const float*)d_in[3];
  const float* lng  = (const float*)d_in[4];
  const float* lnb  = (const float*)d_in[5];
  const float* W1   = (const float*)d_in[6];
  const float* b1   = (const float*)d_in[7];
  const float* W2   = (const float*)d_in[8];
  const float* b2   = (const float*)d_in[9];
  const float* W3   = (const float*)d_in[10];
  const float* b3   = (const float*)d_in[11];

  char* ws = (char*)d_ws;
  u16* y    = (u16*)(ws + OFF_Y);
  u16* w1t  = (u16*)(ws + OFF_W1T);
  u16* w2t  = (u16*)(ws + OFF_W2T);
  int* tok  = (int*)(ws + OFF_TOK);
  int* meta = (int*)(ws + OFF_META);
  int* counts2d  = meta;           // 8192 ints
  int* offsets   = meta + 8192;    // 65 ints
  int* tileHead  = meta + 8320;    // 1024 ints
  int* tileRow   = meta + 9344;    // 1024 ints
  int* nTiles    = meta + 10368;
  int* propFlag  = meta + 10369;
  int* cursors_p = meta + 10432;   // 1024 ints (64 bins, 64B-padded)

  setup_kernel<<<128, 256, 0, stream>>>(prop, mask, (u32*)d_out, counts2d,
                                        cursors_p, propFlag);
  transpose_w1<<<768, 256, 0, stream>>>(W1, w1t);
  transpose_kernel<<<64 * 8 * 4, 256, 0, stream>>>(W2, w2t, GH, GH2, 4);
  ln_kernel<<<NTOK / 4, 256, 0, stream>>>(hs, lng, lnb, prop, y, propFlag);
  scan_kernel<<<1, 64, 0, stream>>>(counts2d, offsets, tileHead, tileRow, nTiles);
  scatter_kernel<<<NTOK / 256, 256, 0, stream>>>(prop, mask, offsets, cursors_p, tok, propFlag);
  adapter_gemm<<<640, 256, 0, stream>>>(y, w1t, w2t, b1, b2, W3, b3, base, mask,
                                        tok, offsets, tileHead, tileRow, nTiles,
                                        (float*)d_out);
}